// Round 1
// baseline (236.044 us; speedup 1.0000x reference)
//
#include <hip/hip_runtime.h>
#include <math.h>

#define N_Q 4096
#define L_K 64
#define M_D 256
#define H_H 8

typedef float f32x16 __attribute__((ext_vector_type(16)));
typedef __bf16 b16x8 __attribute__((ext_vector_type(8)));

union F8 { uint4 u; unsigned short s[8]; b16x8 v; };

__device__ __forceinline__ unsigned short f2bf(float x) {
  unsigned u = __float_as_uint(x);
  return (unsigned short)((u + 0x7fffu + ((u >> 16) & 1u)) >> 16);  // RNE
}

// ---------------- kernel 1: detect is_specified element width ----------------
// int32 layout: bytes at offset i (i%4!=0) are always 0 (values are 0/1 LE).
// u8/bool layout: those bytes are random 0/1 -> some nonzero among 3072 checked.
__global__ void k_detect(const unsigned char* __restrict__ raw, int* __restrict__ flag) {
  int v = 0;
  for (int i = threadIdx.x; i < 4096; i += 256)
    if (i & 3) v |= raw[i];
  int any = __syncthreads_or(v);
  if (threadIdx.x == 0) flag[0] = any ? 1 : 0;   // 1 = byte layout, 0 = int32
}

// ------------- kernel 2: canonicalize spec, write output chunk 2, Wv^T -------------
__global__ void k_prep(const unsigned char* __restrict__ raw, const int* __restrict__ flag,
                       unsigned char* __restrict__ spec, float* __restrict__ out2,
                       const float* __restrict__ wv, float* __restrict__ wvt) {
  int gi = blockIdx.x * 256 + threadIdx.x;
  int f = flag[0];
  if (gi < N_Q * L_K) {
    bool b = f ? (raw[gi] != 0) : (((const int*)raw)[gi] != 0);
    spec[gi] = b ? 1 : 0;
    out2[gi] = b ? 1.0f : 0.0f;
  }
  if (gi < M_D * M_D) {
    int m = gi >> 8, j = gi & 255;
    wvt[j * M_D + m] = wv[m * M_D + j];
  }
}

// ---------------- kernel 3: K-projection GEMM + RoPE + scores + softmax ----------------
// Block: 512 threads (8 waves), 256 rows ((n,l) pairs = 4 full n), all 256 cols.
// Wave: 32 rows, 8 col-tiles of 32, mfma_f32_32x32x16_bf16, acc = 8 x f32x16.
#define KEP_STRIDE 132
#define KEP_WAVE   (32 * KEP_STRIDE)      // 4224 words / wave
#define SC_OFF     135168                 // kep region: 8*4224*4 = 135168 B
#define FR_OFF     (SC_OFF + 8192)        // score_s: 4n*8h*64l*4 = 8192 B
#define LDS_SZ     (FR_OFF + 1536)        // freqs: 384*4 B  -> 144896 B total

__global__ __launch_bounds__(512) void k_scores(
    const float* __restrict__ sv, const int* __restrict__ lin,
    const float* __restrict__ q, const float* __restrict__ wk,
    const float* __restrict__ pos, const float* __restrict__ freqs,
    const unsigned char* __restrict__ spec, float* __restrict__ attn) {
  __shared__ __align__(16) char smem[LDS_SZ];
  float* score_s = (float*)(smem + SC_OFF);
  float* fr = (float*)(smem + FR_OFF);
  const int tid = threadIdx.x, lane = tid & 63, w = tid >> 6;

  if (tid < 384) fr[tid] = freqs[tid];

  // Stage Wk f32 -> bf16 into LDS, layout [n][k] with G4 XOR swizzle on k-bytes.
  for (int it = 0; it < 16; ++it) {
    int Gp = tid + (it << 9);              // 8192 groups of 8 elems
    int n = Gp >> 5, k0 = (Gp & 31) << 3;
    const float4* p = (const float4*)(wk + n * 256 + k0);
    float4 f0 = p[0], f1 = p[1];
    F8 pk;
    pk.s[0] = f2bf(f0.x); pk.s[1] = f2bf(f0.y); pk.s[2] = f2bf(f0.z); pk.s[3] = f2bf(f0.w);
    pk.s[4] = f2bf(f1.x); pk.s[5] = f2bf(f1.y); pk.s[6] = f2bf(f1.z); pk.s[7] = f2bf(f1.w);
    *(uint4*)(smem + n * 512 + (((unsigned)(k0 << 1)) ^ ((n & 7) << 4))) = pk.u;
  }

  const int row = blockIdx.x * 256 + w * 32 + (lane & 31);   // flat (n,l): row = n*64+l
  const int kg = lane >> 5;                                   // k-half for A/B frags
  const float* arow = sv + (size_t)lin[row] * 256;

  __syncthreads();

  f32x16 acc[8];
  #pragma unroll
  for (int t = 0; t < 8; ++t)
    #pragma unroll
    for (int r = 0; r < 16; ++r) acc[t][r] = 0.0f;

  float4 a0 = *(const float4*)(arow + kg * 8);
  float4 a1 = *(const float4*)(arow + kg * 8 + 4);
  #pragma unroll 1
  for (int ks = 0; ks < 16; ++ks) {
    int nks = (ks < 15) ? ks + 1 : 15;                        // 1-deep prefetch
    float4 n0 = *(const float4*)(arow + nks * 16 + kg * 8);
    float4 n1 = *(const float4*)(arow + nks * 16 + kg * 8 + 4);
    F8 af;
    af.s[0] = f2bf(a0.x); af.s[1] = f2bf(a0.y); af.s[2] = f2bf(a0.z); af.s[3] = f2bf(a0.w);
    af.s[4] = f2bf(a1.x); af.s[5] = f2bf(a1.y); af.s[6] = f2bf(a1.z); af.s[7] = f2bf(a1.w);
    const unsigned kb2 = (unsigned)((ks * 16 + kg * 8) << 1); // byte offset of k in row
    #pragma unroll
    for (int t = 0; t < 8; ++t) {
      int nc = t * 32 + (lane & 31);                          // B col = Wk row
      F8 bf;
      bf.u = *(const uint4*)(smem + nc * 512 + (kb2 ^ ((nc & 7) << 4)));
      acc[t] = __builtin_amdgcn_mfma_f32_32x32x16_bf16(af.v, bf.v, acc[t], 0, 0, 0);
    }
    a0 = n0; a1 = n1;
  }

  __syncthreads();   // Wk dead; reuse LDS for k-tile transpose

  float* my_kep = (float*)smem + w * KEP_WAVE;

  for (int hp = 0; hp < 2; ++hp) {        // two col-halves: heads hp*4 .. hp*4+3
    #pragma unroll
    for (int tt = 0; tt < 4; ++tt) {
      f32x16 A = acc[hp * 4 + tt];
      #pragma unroll
      for (int r = 0; r < 16; ++r) {
        // D mapping (m74/m101): row = (r&3) + 8*(r>>2) + 4*(lane>>5), col = lane&31
        int rw = ((lane >> 5) << 2) + (r & 3) + ((r >> 2) << 3);
        int cl = tt * 32 + (lane & 31);
        my_kep[rw * KEP_STRIDE + cl + (cl >> 5)] = A[r];
      }
    }
    __syncthreads();
    #pragma unroll
    for (int uu = 0; uu < 2; ++uu) {      // 128 (row,head) units per wave-phase
      int u = lane + (uu << 6);
      int riw = u >> 2, hl = u & 3, h = hp * 4 + hl;
      int rloc = w * 32 + riw;
      int rg = blockIdx.x * 256 + rloc;
      float p0 = pos[rg * 3], p1 = pos[rg * 3 + 1], p2 = pos[rg * 3 + 2];
      int nn = rg >> 6, ll = rg & 63;
      const float* qb = q + nn * 256 + h * 32;
      const float* F0 = fr + h * 16;
      const float* F1 = fr + 128 + h * 16;
      const float* F2 = fr + 256 + h * 16;
      const float* kr = my_kep + riw * KEP_STRIDE + hl * 33;  // cl + (cl>>5) folded
      float s = 0.f;
      #pragma unroll
      for (int d = 0; d < 16; ++d) {
        float ang = p0 * F0[d] + p1 * F1[d] + p2 * F2[d];
        float sn, cs;
        __sincosf(ang, &sn, &cs);
        float ke = kr[2 * d], ko = kr[2 * d + 1];
        float2 qq = *(const float2*)(qb + 2 * d);
        // (ke*c - ko*s)*qe + (ke*s + ko*c)*qo
        s += ke * (cs * qq.x + sn * qq.y) + ko * (cs * qq.y - sn * qq.x);
      }
      score_s[(((rloc >> 6) << 3) + h) * 64 + ll] = s * 0.0625f;   // 1/sqrt(256)
    }
    __syncthreads();
  }

  // masked softmax over l=0..63, one (n,h) unit per wave iteration
  #pragma unroll
  for (int uu = 0; uu < 4; ++uu) {
    int unit = w * 4 + uu;
    int nl = unit >> 3, h = unit & 7;
    int n_g = blockIdx.x * 4 + nl;
    bool sp = spec[n_g * 64 + lane] != 0;
    float v = sp ? score_s[unit * 64 + lane] : -__builtin_inff();
    float mx = v;
    #pragma unroll
    for (int o = 32; o; o >>= 1) mx = fmaxf(mx, __shfl_xor(mx, o));
    float e = sp ? __expf(v - mx) : 0.f;
    float sm = e;
    #pragma unroll
    for (int o = 32; o; o >>= 1) sm += __shfl_xor(sm, o);
    attn[(n_g * 8 + h) * 64 + lane] = (sm > 0.f) ? e / sm : 0.f;  // 0 if no key specified
  }
}

// ---------------- kernel 4: attn-weighted gather + Wv projection (fp32) ----------------
// out[n, h*32+d] = (sum_l attn[n,h,l] * gathered[n,l,:]) . Wv[h*32+d, :]
__global__ __launch_bounds__(256) void k_vout(
    const float* __restrict__ sv, const int* __restrict__ lin,
    const unsigned char* __restrict__ spec, const float* __restrict__ attn,
    const float* __restrict__ wvt, float* __restrict__ out) {
  __shared__ float attn_s[4][64][8];
  __shared__ unsigned char spec_s[256];
  __shared__ float glds[4][8][256];
  const int tid = threadIdx.x;
  const int n0 = blockIdx.x * 4;

  for (int i = tid; i < 2048; i += 256) {
    int nn = i >> 9, h = (i >> 6) & 7, l = i & 63;
    attn_s[nn][l][h] = attn[n0 * 512 + i];
  }
  spec_s[tid] = spec[n0 * 64 + tid];
  __syncthreads();

  float ga[4][8];
  #pragma unroll
  for (int nn = 0; nn < 4; ++nn)
    #pragma unroll
    for (int h = 0; h < 8; ++h) ga[nn][h] = 0.f;

  #pragma unroll
  for (int nn = 0; nn < 4; ++nn) {
    for (int l = 0; l < 64; ++l) {
      if (!spec_s[nn * 64 + l]) continue;        // block-uniform branch
      int ix = lin[(n0 + nn) * 64 + l];
      float gv = sv[(size_t)ix * 256 + tid];     // coalesced column read
      const float4* ap = (const float4*)&attn_s[nn][l][0];
      float4 aA = ap[0], aB = ap[1];
      ga[nn][0] += aA.x * gv; ga[nn][1] += aA.y * gv;
      ga[nn][2] += aA.z * gv; ga[nn][3] += aA.w * gv;
      ga[nn][4] += aB.x * gv; ga[nn][5] += aB.y * gv;
      ga[nn][6] += aB.z * gv; ga[nn][7] += aB.w * gv;
    }
  }
  #pragma unroll
  for (int nn = 0; nn < 4; ++nn)
    #pragma unroll
    for (int h = 0; h < 8; ++h) glds[nn][h][tid] = ga[nn][h];
  __syncthreads();

  const int m = tid, h = m >> 5;
  float acc[4] = {0.f, 0.f, 0.f, 0.f};
  for (int j = 0; j < 256; j += 4) {
    float w0 = wvt[j * 256 + m];
    float w1 = wvt[(j + 1) * 256 + m];
    float w2 = wvt[(j + 2) * 256 + m];
    float w3 = wvt[(j + 3) * 256 + m];
    #pragma unroll
    for (int nn = 0; nn < 4; ++nn) {
      const float4 g4 = *(const float4*)&glds[nn][h][j];
      acc[nn] += g4.x * w0 + g4.y * w1 + g4.z * w2 + g4.w * w3;
    }
  }
  #pragma unroll
  for (int nn = 0; nn < 4; ++nn)
    out[(n0 + nn) * 256 + m] = acc[nn];
}

extern "C" void kernel_launch(void* const* d_in, const int* in_sizes, int n_in,
                              void* d_out, int out_size, void* d_ws, size_t ws_size,
                              hipStream_t stream) {
  const float* sv = (const float*)d_in[0];
  const int* lin = (const int*)d_in[1];
  const unsigned char* raw = (const unsigned char*)d_in[2];
  const float* q = (const float*)d_in[3];
  const float* wk = (const float*)d_in[4];
  const float* wv = (const float*)d_in[5];
  const float* pos = (const float*)d_in[6];
  const float* fq = (const float*)d_in[7];
  float* out = (float*)d_out;
  char* ws = (char*)d_ws;

  int* flag = (int*)ws;                                   // 4 B
  unsigned char* spec = (unsigned char*)(ws + 1024);      // 262144 B
  float* attn = (float*)(ws + 263168);                    // 8388608 B
  float* wvt = (float*)(ws + 8651776);                    // 262144 B  (total ~8.5 MB)

  k_detect<<<1, 256, 0, stream>>>(raw, flag);
  k_prep<<<1024, 256, 0, stream>>>(raw, flag, spec, out + N_Q * M_D, wv, wvt);
  k_scores<<<1024, 512, 0, stream>>>(sv, lin, q, wk, pos, fq, spec, attn);
  k_vout<<<1024, 256, 0, stream>>>(sv, lin, spec, attn, wvt, out);
}

// Round 2
// 234.640 us; speedup vs baseline: 1.0060x; 1.0060x over previous
//
#include <hip/hip_runtime.h>
#include <math.h>

#define N_Q 4096
#define L_K 64
#define M_D 256

typedef float f32x16 __attribute__((ext_vector_type(16)));
typedef __bf16 b16x8 __attribute__((ext_vector_type(8)));
union F8 { uint4 u; unsigned short s[8]; b16x8 v; };

__device__ __forceinline__ unsigned short f2bf(float x) {
  unsigned u = __float_as_uint(x);
  return (unsigned short)((u + 0x7fffu + ((u >> 16) & 1u)) >> 16);  // RNE
}

// ---------------- prep: detect spec layout, canonicalize, echo out2, Wv^T ----------------
// int32 layout: bytes at offset i (i%4!=0) of the first 4KB are all zero (values 0/1 LE).
// byte layout: ~half are 1 -> OR is nonzero. Every block derives the same flag.
__global__ __launch_bounds__(256) void k_prep(const unsigned char* __restrict__ raw,
                                              unsigned char* __restrict__ spec,
                                              float* __restrict__ out2,
                                              const float* __restrict__ wv,
                                              float* __restrict__ wvt) {
  int v = 0;
  for (int i = threadIdx.x; i < 4096; i += 256)
    if (i & 3) v |= raw[i];
  int f = __syncthreads_or(v);          // 1 = byte layout, 0 = int32 layout
  int gi = blockIdx.x * 256 + threadIdx.x;       // grid exactly covers N*L = 262144
  bool b = f ? (raw[gi] != 0) : (((const int*)raw)[gi] != 0);
  spec[gi] = b ? 1 : 0;
  out2[gi] = b ? 1.0f : 0.0f;
  if (gi < 65536) wvt[(gi & 255) * 256 + (gi >> 8)] = wv[gi];   // wvt[j][m] = wv[m][j]
}

// ---------------- fused main kernel ----------------
// 1024 blocks x 512 threads; block owns 4 n (256 (n,l) rows), all 8 heads.
// LDS: [0,64K) Wk k-half (bf16, XOR-swizzled) -> later kep transpose -> later C tile.
#define SC_OFF   65536
#define FR_OFF   (SC_OFF + 8192)
#define LIN_OFF  (FR_OFF + 1536)
#define SPEC_OFF (LIN_OFF + 1024)
#define LDS_SZ   (SPEC_OFF + 256)       // 76544 B -> 2 blocks/CU

__global__ __launch_bounds__(512, 2) void k_main(
    const float* __restrict__ sv, const int* __restrict__ lin,
    const float* __restrict__ q, const float* __restrict__ wk,
    const float* __restrict__ pos, const float* __restrict__ freqs,
    const unsigned char* __restrict__ spec, const float* __restrict__ wvt,
    float* __restrict__ out) {
  __shared__ __align__(16) char smem[LDS_SZ];
  float* score_s = (float*)(smem + SC_OFF);
  float* fr      = (float*)(smem + FR_OFF);
  int*   lin_s   = (int*)(smem + LIN_OFF);
  unsigned char* spec_s = (unsigned char*)(smem + SPEC_OFF);
  const int tid = threadIdx.x, lane = tid & 63, w = tid >> 6;
  const int c32 = lane & 31, kg = lane >> 5;
  const int n0 = blockIdx.x * 4;

  if (tid < 384) fr[tid] = freqs[tid];
  if (tid < 256) {
    lin_s[tid]  = lin[blockIdx.x * 256 + tid];
    spec_s[tid] = spec[blockIdx.x * 256 + tid];
  }

  // stage Wk k-half hh: rows n=0..255, cols [hh*128, hh*128+128) as bf16, 256B/row
  auto stage = [&](int hh) {
    #pragma unroll
    for (int it = 0; it < 8; ++it) {
      int Gp = tid + (it << 9);                 // 0..4095 groups of 8 elems
      int n = Gp >> 4, kl0 = (Gp & 15) << 3;
      const float4* pp = (const float4*)(wk + n * 256 + hh * 128 + kl0);
      float4 f0 = pp[0], f1 = pp[1];
      F8 pk;
      pk.s[0] = f2bf(f0.x); pk.s[1] = f2bf(f0.y); pk.s[2] = f2bf(f0.z); pk.s[3] = f2bf(f0.w);
      pk.s[4] = f2bf(f1.x); pk.s[5] = f2bf(f1.y); pk.s[6] = f2bf(f1.z); pk.s[7] = f2bf(f1.w);
      // full 16-slot XOR swizzle within the 256B row
      *(uint4*)(smem + n * 256 + (((unsigned)(kl0 << 1)) ^ ((n & 15) << 4))) = pk.u;
    }
  };

  stage(0);
  __syncthreads();

  const float* arow = sv + (size_t)lin_s[w * 32 + c32] * 256;

  f32x16 acc[8];
  #pragma unroll
  for (int t = 0; t < 8; ++t)
    #pragma unroll
    for (int r = 0; r < 16; ++r) acc[t][r] = 0.0f;

  auto gemm_pass = [&](int koff) {
    #pragma unroll
    for (int ks = 0; ks < 8; ++ks) {
      const float* ap = arow + koff + ks * 16 + kg * 8;
      float4 a0 = *(const float4*)(ap);
      float4 a1 = *(const float4*)(ap + 4);
      F8 af;
      af.s[0] = f2bf(a0.x); af.s[1] = f2bf(a0.y); af.s[2] = f2bf(a0.z); af.s[3] = f2bf(a0.w);
      af.s[4] = f2bf(a1.x); af.s[5] = f2bf(a1.y); af.s[6] = f2bf(a1.z); af.s[7] = f2bf(a1.w);
      const unsigned kb2 = (unsigned)((ks * 16 + kg * 8) << 1);   // byte offset in 256B row
      #pragma unroll
      for (int t = 0; t < 8; ++t) {
        int nc = t * 32 + c32;
        F8 bf;
        bf.u = *(const uint4*)(smem + nc * 256 + (kb2 ^ ((nc & 15) << 4)));
        acc[t] = __builtin_amdgcn_mfma_f32_32x32x16_bf16(af.v, bf.v, acc[t], 0, 0, 0);
      }
    }
  };

  gemm_pass(0);
  __syncthreads();
  stage(1);
  __syncthreads();
  gemm_pass(128);
  __syncthreads();          // Wk dead; kep overlay begins

  // ---- per-head transpose (wave-private kep) + RoPE + q-dot ----
  const int riw = lane >> 1, dh = lane & 1;
  const int row_g = blockIdx.x * 256 + w * 32 + riw;
  const int nn_ = row_g >> 6, ll = row_g & 63;
  const float pp0 = pos[row_g * 3], pp1 = pos[row_g * 3 + 1], pp2 = pos[row_g * 3 + 2];
  float* kep = (float*)smem + w * 1056;   // 32 rows x stride 33 f32, per wave

  #pragma unroll
  for (int h = 0; h < 8; ++h) {
    #pragma unroll
    for (int r = 0; r < 16; ++r) {
      int rw = ((lane >> 5) << 2) + (r & 3) + ((r >> 2) << 3);   // m74/m101 D-layout
      kep[rw * 33 + c32] = acc[h][r];
    }
    asm volatile("s_waitcnt lgkmcnt(0)" ::: "memory");  // wave-private write->read
    const float* kr = kep + riw * 33 + (dh << 4);
    const float* qb = q + nn_ * 256 + h * 32 + (dh << 4);
    const float* F0 = fr + h * 16 + (dh << 3);
    const float* F1 = F0 + 128;
    const float* F2 = F0 + 256;
    float s = 0.f;
    #pragma unroll
    for (int j = 0; j < 8; ++j) {
      float ang = pp0 * F0[j] + pp1 * F1[j] + pp2 * F2[j];
      float sn, cs;
      __sincosf(ang, &sn, &cs);
      float ke = kr[2 * j], ko = kr[2 * j + 1];
      float2 qq = *(const float2*)(qb + 2 * j);
      s += ke * (cs * qq.x + sn * qq.y) + ko * (cs * qq.y - sn * qq.x);
    }
    s += __shfl_xor(s, 1);
    if (dh == 0)
      score_s[(((w >> 1) << 3) + h) * 64 + ((w & 1) << 5) + riw] = s * 0.0625f;
    asm volatile("s_waitcnt lgkmcnt(0)" ::: "memory");  // drain reads before next overwrite
  }

  __syncthreads();

  // ---- masked softmax, in place: score_s becomes attn ----
  #pragma unroll
  for (int uu = 0; uu < 4; ++uu) {
    int unit = w * 4 + uu;                    // (nl*8 + h)
    int nl = unit >> 3;
    bool sp = spec_s[nl * 64 + lane] != 0;
    float v = sp ? score_s[unit * 64 + lane] : -__builtin_inff();
    float mx = v;
    #pragma unroll
    for (int o = 32; o; o >>= 1) mx = fmaxf(mx, __shfl_xor(mx, o));
    float e = sp ? __expf(v - mx) : 0.f;
    float sm = e;
    #pragma unroll
    for (int o = 32; o; o >>= 1) sm += __shfl_xor(sm, o);
    score_s[unit * 64 + lane] = (sm > 0.f) ? e / sm : 0.f;
  }
  __syncthreads();

  // ---- V aggregation: C[(nn,h), m] = sum_l attn * g[n,l,m]  (fp32) ----
  float* Cld = (float*)smem;                 // 32 x 256 f32 = 32KB, overlays dead kep/Wk
  const int m = tid & 255, g2 = tid >> 8;
  float ga[2][8];
  #pragma unroll
  for (int a = 0; a < 2; ++a)
    #pragma unroll
    for (int h = 0; h < 8; ++h) ga[a][h] = 0.f;

  #pragma unroll
  for (int nn2 = 0; nn2 < 2; ++nn2) {
    const int nn = g2 * 2 + nn2;
    const float* asrc = score_s + nn * 512;  // attn, 8h x 64l
    for (int l = 0; l < 64; ++l) {
      if (!spec_s[nn * 64 + l]) continue;    // uniform across the 256-thread group
      float gv = sv[(size_t)lin_s[nn * 64 + l] * 256 + m];
      #pragma unroll
      for (int h = 0; h < 8; ++h) ga[nn2][h] += asrc[h * 64 + l] * gv;
    }
  }
  #pragma unroll
  for (int nn2 = 0; nn2 < 2; ++nn2)
    #pragma unroll
    for (int h = 0; h < 8; ++h)
      Cld[((g2 * 2 + nn2) * 8 + h) * 256 + m] = ga[nn2][h];
  __syncthreads();

  // ---- out projection: out[n, m] = sum_mm C[(n, m>>5), mm] * Wv[m, mm] ----
  const int nb = g2;
  const float* c0 = Cld + (nb * 8 + (m >> 5)) * 256;
  const float* c1 = Cld + ((nb + 2) * 8 + (m >> 5)) * 256;
  float o0 = 0.f, o1 = 0.f;
  for (int mm = 0; mm < 256; ++mm) {
    float wvv = wvt[mm * 256 + m];           // coalesced; L2-hot
    o0 += c0[mm] * wvv;                      // LDS broadcast reads
    o1 += c1[mm] * wvv;
  }
  out[(n0 + nb) * 256 + m] = o0;
  out[(n0 + nb + 2) * 256 + m] = o1;
}

extern "C" void kernel_launch(void* const* d_in, const int* in_sizes, int n_in,
                              void* d_out, int out_size, void* d_ws, size_t ws_size,
                              hipStream_t stream) {
  const float* sv  = (const float*)d_in[0];
  const int* lin   = (const int*)d_in[1];
  const unsigned char* raw = (const unsigned char*)d_in[2];
  const float* q   = (const float*)d_in[3];
  const float* wk  = (const float*)d_in[4];
  const float* wv  = (const float*)d_in[5];
  const float* pos = (const float*)d_in[6];
  const float* fq  = (const float*)d_in[7];
  float* out = (float*)d_out;
  char* ws = (char*)d_ws;

  unsigned char* spec = (unsigned char*)ws;               // 262144 B
  float* wvt = (float*)(ws + 262144);                     // 262144 B

  k_prep<<<1024, 256, 0, stream>>>(raw, spec, out + N_Q * M_D, wv, wvt);
  k_main<<<1024, 512, 0, stream>>>(sv, lin, q, wk, pos, fq, spec, wvt, out);
}

// Round 3
// 144.227 us; speedup vs baseline: 1.6366x; 1.6269x over previous
//
#include <hip/hip_runtime.h>
#include <math.h>

#define N_Q 4096
#define L_K 64
#define M_D 256

typedef float f32x16 __attribute__((ext_vector_type(16)));
typedef __bf16 b16x8 __attribute__((ext_vector_type(8)));
union F8 { uint4 u; unsigned short s[8]; b16x8 v; };

__device__ __forceinline__ unsigned short f2bf(float x) {
  unsigned u = __float_as_uint(x);
  return (unsigned short)((u + 0x7fffu + ((u >> 16) & 1u)) >> 16);  // RNE
}

// ---------------- prep: detect spec layout, canonicalize, out2, Wv^T, Wk->bf16 image ----------------
__global__ __launch_bounds__(256) void k_prep(const unsigned char* __restrict__ raw,
                                              unsigned char* __restrict__ spec,
                                              float* __restrict__ out2,
                                              const float* __restrict__ wv,
                                              float* __restrict__ wvt,
                                              const float* __restrict__ wk,
                                              unsigned short* __restrict__ wkb) {
  int v = 0;
  for (int i = threadIdx.x; i < 4096; i += 256)
    if (i & 3) v |= raw[i];
  int f = __syncthreads_or(v);          // 1 = byte layout, 0 = int32 layout
  int gi = blockIdx.x * 256 + threadIdx.x;       // covers N*L = 262144
  bool b = f ? (raw[gi] != 0) : (((const int*)raw)[gi] != 0);
  spec[gi] = b ? 1 : 0;
  out2[gi] = b ? 1.0f : 0.0f;
  if (gi < 65536) {
    wvt[(gi & 255) * 256 + (gi >> 8)] = wv[gi];            // wvt[j][m] = wv[m][j]
    // Wk bf16 image, pre-swizzled: half hh (k-cols hh*128..+127), row n, 256B rows.
    int n = gi >> 8, k = gi & 255;
    int hh = k >> 7, kl = k & 127;
    int slot = kl >> 3, bib = (kl & 7) << 1;
    int soff = hh * 65536 + n * 256 + (((slot ^ (n & 15)) << 4) | bib);
    *(unsigned short*)((char*)wkb + soff) = f2bf(wk[gi]);
  }
}

// ---------------- k_scores: K-proj GEMM + RoPE + scores + softmax -> attn ----------------
// 2048 blocks x 512 threads (8 waves). Block owns 128 rows (2 n), 256 cols.
// Wave (rg = w>>1, ch = w&1): rows rg*32..+31, col-tiles ch*4..ch*4+3 (heads ch*4..+3).
// acc = 4 x f32x16 = 64 regs -> ~120 total/wave -> 4 waves/SIMD -> 2 blocks/CU.
#define SC_OFF   65536
#define FR_OFF   (SC_OFF + 4096)
#define SPEC_OFF (FR_OFF + 1536)
#define LDS_SZ   (SPEC_OFF + 128)       // 71296 B -> 2 blocks/CU

__global__ __launch_bounds__(512, 4) void k_scores(
    const float* __restrict__ sv, const int* __restrict__ lin,
    const float* __restrict__ q, const unsigned short* __restrict__ wkb,
    const float* __restrict__ pos, const float* __restrict__ freqs,
    const unsigned char* __restrict__ spec, float* __restrict__ attn) {
  __shared__ __align__(16) char smem[LDS_SZ];
  float* score_s = (float*)(smem + SC_OFF);     // 2n x 8h x 64l
  float* fr      = (float*)(smem + FR_OFF);
  unsigned char* spec_s = (unsigned char*)(smem + SPEC_OFF);
  const int tid = threadIdx.x, lane = tid & 63, w = tid >> 6;
  const int c32 = lane & 31, kg = lane >> 5;
  const int rg = w >> 1, ch = w & 1;

  if (tid < 384) fr[tid] = freqs[tid];
  if (tid < 128) spec_s[tid] = spec[blockIdx.x * 128 + tid];

  // stage Wk k-half hh: pure 64KB copy (image already bf16 + swizzled)
  auto stage = [&](int hh) {
    #pragma unroll
    for (int it = 0; it < 8; ++it) {
      int off = (tid << 4) + (it << 13);
      *(uint4*)(smem + off) = *(const uint4*)((const char*)wkb + hh * 65536 + off);
    }
  };

  const int row_l = rg * 32 + c32;
  const float* arow = sv + (size_t)lin[blockIdx.x * 128 + row_l] * 256;

  stage(0);
  __syncthreads();

  f32x16 acc[4];
  #pragma unroll
  for (int t = 0; t < 4; ++t)
    #pragma unroll
    for (int r = 0; r < 16; ++r) acc[t][r] = 0.0f;

  auto gemm_pass = [&](int koff) {
    #pragma unroll
    for (int ks = 0; ks < 8; ++ks) {
      const float* ap = arow + koff + ks * 16 + kg * 8;
      float4 a0 = *(const float4*)(ap);
      float4 a1 = *(const float4*)(ap + 4);
      F8 af;
      af.s[0] = f2bf(a0.x); af.s[1] = f2bf(a0.y); af.s[2] = f2bf(a0.z); af.s[3] = f2bf(a0.w);
      af.s[4] = f2bf(a1.x); af.s[5] = f2bf(a1.y); af.s[6] = f2bf(a1.z); af.s[7] = f2bf(a1.w);
      const unsigned kb2 = (unsigned)((ks * 16 + kg * 8) << 1);   // byte offset in 256B row
      #pragma unroll
      for (int t = 0; t < 4; ++t) {
        int nc = (ch * 4 + t) * 32 + c32;
        F8 bf;
        bf.u = *(const uint4*)(smem + nc * 256 + (kb2 ^ ((nc & 15) << 4)));
        acc[t] = __builtin_amdgcn_mfma_f32_32x32x16_bf16(af.v, bf.v, acc[t], 0, 0, 0);
      }
    }
  };

  gemm_pass(0);
  __syncthreads();
  stage(1);
  __syncthreads();
  gemm_pass(128);
  __syncthreads();          // Wk dead; kep overlay begins

  // ---- per-head transpose (wave-private kep) + RoPE + q-dot ----
  const int riw = lane >> 1, dh = lane & 1;
  const int row_w = rg * 32 + riw;                       // block-local flat row
  const int rg_g = blockIdx.x * 128 + row_w;             // global flat (n,l)
  const int nn_ = rg_g >> 6;
  const float pp0 = pos[rg_g * 3], pp1 = pos[rg_g * 3 + 1], pp2 = pos[rg_g * 3 + 2];
  float* kep = (float*)smem + w * 1056;                  // 32 rows x stride 33, per wave

  #pragma unroll
  for (int hl = 0; hl < 4; ++hl) {
    const int h = ch * 4 + hl;
    #pragma unroll
    for (int r = 0; r < 16; ++r) {
      int rw = ((lane >> 5) << 2) + (r & 3) + ((r >> 2) << 3);   // m74/m101 D-layout
      kep[rw * 33 + c32] = acc[hl][r];
    }
    asm volatile("s_waitcnt lgkmcnt(0)" ::: "memory");
    const float* kr = kep + riw * 33 + (dh << 4);
    const float* qb = q + nn_ * 256 + h * 32 + (dh << 4);
    const float* F0 = fr + h * 16 + (dh << 3);
    const float* F1 = F0 + 128;
    const float* F2 = F0 + 256;
    float s = 0.f;
    #pragma unroll
    for (int j = 0; j < 8; ++j) {
      float ang = pp0 * F0[j] + pp1 * F1[j] + pp2 * F2[j];
      float sn, cs;
      __sincosf(ang, &sn, &cs);
      float ke = kr[2 * j], ko = kr[2 * j + 1];
      float2 qq = *(const float2*)(qb + 2 * j);
      s += ke * (cs * qq.x + sn * qq.y) + ko * (cs * qq.y - sn * qq.x);
    }
    s += __shfl_xor(s, 1);
    if (dh == 0)
      score_s[(((row_w >> 6) << 3) + h) * 64 + (row_w & 63)] = s * 0.0625f;
    asm volatile("s_waitcnt lgkmcnt(0)" ::: "memory");
  }

  __syncthreads();

  // ---- masked softmax: 16 units (2n x 8h), 2 per wave ----
  #pragma unroll
  for (int uu = 0; uu < 2; ++uu) {
    int unit = w * 2 + uu;                    // nl*8 + h
    int nl = unit >> 3, h = unit & 7;
    int n_g = blockIdx.x * 2 + nl;
    bool sp = spec_s[nl * 64 + lane] != 0;
    float v = sp ? score_s[unit * 64 + lane] : -__builtin_inff();
    float mx = v;
    #pragma unroll
    for (int o = 32; o; o >>= 1) mx = fmaxf(mx, __shfl_xor(mx, o));
    float e = sp ? __expf(v - mx) : 0.f;
    float sm = e;
    #pragma unroll
    for (int o = 32; o; o >>= 1) sm += __shfl_xor(sm, o);
    attn[(n_g * 8 + h) * 64 + lane] = (sm > 0.f) ? e / sm : 0.f;
  }
}

// ---------------- k_vout: compacted attn-weighted gather + Wv projection ----------------
// 2048 blocks x 256 threads, 2 n per block. ~21KB LDS -> high occupancy.
__global__ __launch_bounds__(256, 6) void k_vout(
    const float* __restrict__ sv, const int* __restrict__ lin,
    const unsigned char* __restrict__ spec, const float* __restrict__ attn,
    const float* __restrict__ wvt, float* __restrict__ out) {
  __shared__ float attn_s[2][64][8];       // 4KB  [nn][l][h]
  __shared__ float agg_s[2][8][256];       // 16KB
  __shared__ int list_s[2][64];
  __shared__ int cnt_s[2];
  __shared__ int lin_l[128];
  __shared__ unsigned char spec_l[128];
  const int tid = threadIdx.x, lane = tid & 63, w = tid >> 6;
  const int n0 = blockIdx.x * 2;

  #pragma unroll
  for (int it = 0; it < 4; ++it) {
    int i = tid + it * 256;                // i = nn*512 + h*64 + l
    attn_s[i >> 9][i & 63][(i >> 6) & 7] = attn[n0 * 512 + i];
  }
  if (tid < 128) {
    lin_l[tid] = lin[n0 * 64 + tid];
    spec_l[tid] = spec[n0 * 64 + tid];
  }
  __syncthreads();

  if (w == 0) {                            // build packed gather lists
    #pragma unroll
    for (int nn = 0; nn < 2; ++nn) {
      bool p = spec_l[nn * 64 + lane] != 0;
      unsigned long long mask = __ballot(p);
      if (p) {
        int rank = __popcll(mask & ((1ull << lane) - 1));
        list_s[nn][rank] = (lin_l[nn * 64 + lane] << 6) | lane;
      }
      if (lane == 0) cnt_s[nn] = __popcll(mask);
    }
  }
  __syncthreads();

  const int m = tid;
  float ga[2][8];
  #pragma unroll
  for (int a = 0; a < 2; ++a)
    #pragma unroll
    for (int h = 0; h < 8; ++h) ga[a][h] = 0.f;

  #pragma unroll
  for (int nn = 0; nn < 2; ++nn) {
    const int cnt = cnt_s[nn];
    #pragma unroll 4
    for (int i = 0; i < cnt; ++i) {
      int pk = list_s[nn][i];
      float gv = sv[(size_t)(pk >> 6) * 256 + m];          // coalesced 1KB row
      const float4* ap = (const float4*)&attn_s[nn][pk & 63][0];
      float4 aA = ap[0], aB = ap[1];
      ga[nn][0] += aA.x * gv; ga[nn][1] += aA.y * gv;
      ga[nn][2] += aA.z * gv; ga[nn][3] += aA.w * gv;
      ga[nn][4] += aB.x * gv; ga[nn][5] += aB.y * gv;
      ga[nn][6] += aB.z * gv; ga[nn][7] += aB.w * gv;
    }
  }
  #pragma unroll
  for (int nn = 0; nn < 2; ++nn)
    #pragma unroll
    for (int h = 0; h < 8; ++h) agg_s[nn][h][m] = ga[nn][h];
  __syncthreads();

  const int h = m >> 5;
  const float* a0p = &agg_s[0][h][0];
  const float* a1p = &agg_s[1][h][0];
  float o0 = 0.f, o1 = 0.f;
  #pragma unroll 8
  for (int mm = 0; mm < 256; ++mm) {
    float wvv = wvt[mm * 256 + m];         // coalesced, L2-hot
    o0 += a0p[mm] * wvv;                   // LDS broadcast reads
    o1 += a1p[mm] * wvv;
  }
  out[n0 * 256 + m] = o0;
  out[(n0 + 1) * 256 + m] = o1;
}

extern "C" void kernel_launch(void* const* d_in, const int* in_sizes, int n_in,
                              void* d_out, int out_size, void* d_ws, size_t ws_size,
                              hipStream_t stream) {
  const float* sv  = (const float*)d_in[0];
  const int* lin   = (const int*)d_in[1];
  const unsigned char* raw = (const unsigned char*)d_in[2];
  const float* q   = (const float*)d_in[3];
  const float* wk  = (const float*)d_in[4];
  const float* wv  = (const float*)d_in[5];
  const float* pos = (const float*)d_in[6];
  const float* fq  = (const float*)d_in[7];
  float* out = (float*)d_out;
  char* ws = (char*)d_ws;

  unsigned char* spec = (unsigned char*)ws;               // 262144 B
  float* wvt = (float*)(ws + 262144);                     // 262144 B
  unsigned short* wkb = (unsigned short*)(ws + 524288);   // 131072 B
  float* attn = (float*)(ws + 655360);                    // 8388608 B (total ~9 MB)

  k_prep<<<1024, 256, 0, stream>>>(raw, spec, out + N_Q * M_D, wv, wvt, wk, wkb);
  k_scores<<<2048, 512, 0, stream>>>(sv, lin, q, wkb, pos, fq, spec, attn);
  k_vout<<<2048, 256, 0, stream>>>(sv, lin, spec, attn, wvt, out);
}